// Round 10
// baseline (189.286 us; speedup 1.0000x reference)
//
#include <hip/hip_runtime.h>

#define C_IN   64
#define C_OUT  128
#define Himg   128
#define Wimg   128
#define HW     (Himg * Wimg)
#define TROWS  8
#define TCOLS  32
#define HROWS  10   // TROWS+2
#define HCOLS  34   // TCOLS+2
#define XKSTR  5440            // 340 cells * 16 B per k-group
#define WS_TAP 16384

// padded bf16 cell image: [img][kg 8][y' 130][x' 130] cells of 8 ch (16 B)
#define XB_ROW   1040          // ushorts per padded row (130 cells * 8)
#define XB_KG    135200        // ushorts per kg slice (130 rows)
#define XB_IMG   1081600       // ushorts per image (8 kg)
#define XB_OFF   163840        // byte offset of xb within d_ws (wt occupies first 144K)
#define WS_NEED  (XB_OFF + (size_t)36 * XB_IMG * 2)

typedef __bf16 bf16x8 __attribute__((ext_vector_type(8)));
typedef float  f32x16 __attribute__((ext_vector_type(16)));

__device__ __forceinline__ unsigned int pack2(float a, float b) {
  union { __bf16 h; unsigned short s; } ua, ub;
  ua.h = (__bf16)a; ub.h = (__bf16)b;
  return (unsigned int)ua.s | ((unsigned int)ub.s << 16);
}

__device__ __forceinline__ void gload_lds16(const void* g, void* l) {
  __builtin_amdgcn_global_load_lds((const __attribute__((address_space(1))) void*)g,
                                   (__attribute__((address_space(3))) void*)l, 16, 0, 0);
}

// fp32 W[co][c][3][3] -> bf16 wt, k-major 16B cells: wt[tap][c>>3][co][c&7]
__global__ void wt_transform(const float* __restrict__ w, unsigned short* __restrict__ wt) {
  const int idx = blockIdx.x * 256 + threadIdx.x;
  if (idx >= 9 * C_OUT * C_IN) return;
  const int c   = idx & 63;
  const int co  = (idx >> 6) & 127;
  const int tap = idx >> 13;
  const int ky = tap / 3, kx = tap % 3;
  const float f = w[((co * C_IN + c) * 3 + ky) * 3 + kx];
  union { __bf16 h; unsigned short s; } u; u.h = (__bf16)f;
  wt[tap * 8192 + (c >> 3) * 1024 + co * 8 + (c & 7)] = u.s;
}

// fp32 x[img][c][y][x] -> padded bf16 cells xb[img][kg][y'][x'], one thread per cell
__global__ void xcvt(const float* __restrict__ xin, unsigned short* __restrict__ xb) {
  const int idx = blockIdx.x * 256 + threadIdx.x;
  if (idx >= 36 * 8 * 130 * 130) return;
  const int xp  = idx % 130;
  const int yp  = (idx / 130) % 130;
  const int kg  = (idx / (130 * 130)) & 7;
  const int img = idx / (130 * 130 * 8);
  const int x = xp - 1, y = yp - 1;
  float f[8] = {0.f, 0.f, 0.f, 0.f, 0.f, 0.f, 0.f, 0.f};
  if (x >= 0 && x < Wimg && y >= 0 && y < Himg) {
    const float* p = xin + ((size_t)img * C_IN + kg * 8) * HW + (size_t)y * Wimg + x;
    #pragma unroll
    for (int j = 0; j < 8; ++j) f[j] = p[(size_t)j * HW];
  }
  uint4 cell;
  cell.x = pack2(f[0], f[1]); cell.y = pack2(f[2], f[3]);
  cell.z = pack2(f[4], f[5]); cell.w = pack2(f[6], f[7]);
  *(uint4*)(xb + (size_t)idx * 8) = cell;
}

// ---------------- main conv kernel, pre-converted X path ----------------
__global__ __launch_bounds__(512, 4)
void conv_pre(const unsigned short* __restrict__ xb, const unsigned short* __restrict__ wt,
              const float* __restrict__ bias, float* __restrict__ out) {
  __shared__ __align__(16) unsigned char Xs[8 * XKSTR];    // 43520: [kg][cell 340] 16B cells
  __shared__ __align__(16) unsigned char Ws[2][WS_TAP];    // 32768: [kidx][co] 16B cells

  const int tid = threadIdx.x;
  // bijective XCD swizzle: 2304 = 8 * 288
  const int wg  = (blockIdx.x & 7) * 288 + (blockIdx.x >> 3);
  const int bx  = wg & 3;
  const int by  = (wg >> 2) & 15;
  const int img = wg >> 6;
  const int gy0 = by * TROWS;
  const int gx0 = bx * TCOLS;
  const int lane = tid & 63;
  const int wv   = tid >> 6;    // 0..7

  // ---- issue async Ws tap-0 staging; X copy below covers its latency ----
  {
    const unsigned short* s0 = wt + lane * 8;
    #pragma unroll
    for (int j = 0; j < 2; ++j) {
      const int i = wv * 2 + j;
      gload_lds16(s0 + i * 512, &Ws[0][i * 1024]);
    }
  }

  // ---- stage X tile: pure bf16 cell copy, no converts, no branches ----
  {
    const unsigned short* ib = xb + (size_t)img * XB_IMG + (size_t)gy0 * XB_ROW + gx0 * 8;
    for (int i = tid; i < 2720; i += 512) {       // 8 kg * 340 cells
      const int kg = i / 340;
      const int rc = i - kg * 340;                // r*34 + ci
      const int r  = rc / 34;
      const int ci = rc - r * 34;
      const uint4 cell = *(const uint4*)(ib + (size_t)kg * XB_KG + r * XB_ROW + ci * 8);
      *(uint4*)(&Xs[kg * XKSTR + rc * 16]) = cell;
    }
  }

  // wave tile: 64 co (wm) x 64 px (rows wn*2, wn*2+1)
  const int lpx = lane & 31;
  const int lkh = lane >> 5;
  const int wm  = wv & 1;
  const int wn  = wv >> 1;    // 0..3

  f32x16 acc[2][2];
  #pragma unroll
  for (int mf = 0; mf < 2; ++mf)
    #pragma unroll
    for (int nf = 0; nf < 2; ++nf)
      acc[mf][nf] = (f32x16)(0.f);

  const int abase = lkh * 2048 + (wm * 64 + lpx) * 16;   // + mf*512 + ks*4096
  const int xbase = lkh * XKSTR;                          // + ks*2*XKSTR + cell*16

  __syncthreads();   // Xs + Ws[0] ready

  for (int t = 0; t < 9; ++t) {
    if (t < 8) {   // async-prefetch tap t+1 (buffer last read in tap t-1; barrier-safe)
      const unsigned short* sn = wt + (t + 1) * 8192 + lane * 8;
      unsigned char* db = Ws[(t + 1) & 1];
      #pragma unroll
      for (int j = 0; j < 2; ++j) {
        const int i = wv * 2 + j;
        gload_lds16(sn + i * 512, &db[i * 1024]);
      }
    }
    const int dy = (t >= 6) ? 2 : (t >= 3 ? 1 : 0);
    const int dx = t - dy * 3;
    const unsigned char* wsb = Ws[t & 1];
    int boff[2];
    #pragma unroll
    for (int nf = 0; nf < 2; ++nf)
      boff[nf] = xbase + ((wn * 2 + nf + dy) * HCOLS + dx + lpx) * 16;
    #pragma unroll
    for (int sh = 0; sh < 2; ++sh) {
      bf16x8 A[2][2], B[2][2];
      #pragma unroll
      for (int ss = 0; ss < 2; ++ss) {
        const int ks = sh * 2 + ss;
        #pragma unroll
        for (int mf = 0; mf < 2; ++mf)
          A[mf][ss] = *(const bf16x8*)&Ws[t & 1][abase + mf * 512 + ks * 4096];
        #pragma unroll
        for (int nf = 0; nf < 2; ++nf)
          B[nf][ss] = *(const bf16x8*)&Xs[boff[nf] + ks * 2 * XKSTR];
      }
      __builtin_amdgcn_s_setprio(1);
      #pragma unroll
      for (int ss = 0; ss < 2; ++ss)
        #pragma unroll
        for (int mf = 0; mf < 2; ++mf)
          #pragma unroll
          for (int nf = 0; nf < 2; ++nf)
            acc[mf][nf] = __builtin_amdgcn_mfma_f32_32x32x16_bf16(A[mf][ss], B[nf][ss], acc[mf][nf], 0, 0, 0);
      __builtin_amdgcn_s_setprio(0);
    }
    __syncthreads();
  }

  // ---- epilogue: bias + fp32 full-line stores ----
  float4 bq[2][4];
  #pragma unroll
  for (int mf = 0; mf < 2; ++mf)
    #pragma unroll
    for (int rq = 0; rq < 4; ++rq)
      bq[mf][rq] = *(const float4*)(bias + wm * 64 + mf * 32 + rq * 8 + lkh * 4);

  #pragma unroll
  for (int nf = 0; nf < 2; ++nf) {
    const int y = gy0 + wn * 2 + nf;
    float* op = out + (size_t)img * C_OUT * HW + (size_t)y * Wimg + gx0 + lpx;
    #pragma unroll
    for (int mf = 0; mf < 2; ++mf) {
      #pragma unroll
      for (int r = 0; r < 16; ++r) {
        const int co = wm * 64 + mf * 32 + (r & 3) + 8 * (r >> 2) + lkh * 4;
        op[(size_t)co * HW] = acc[mf][nf][r] + ((const float*)&bq[mf][r >> 2])[r & 3];
      }
    }
  }
}

// ---------------- fallback: exact round-8 kernel (fp32 in-kernel staging) ----------------
__global__ __launch_bounds__(512, 4)
void conv_fb(const float* __restrict__ xin, const unsigned short* __restrict__ wt,
             const float* __restrict__ bias, float* __restrict__ out) {
  __shared__ __align__(16) unsigned char Xs[8 * XKSTR];
  __shared__ __align__(16) unsigned char Ws[2][WS_TAP];

  const int tid = threadIdx.x;
  const int wg  = (blockIdx.x & 7) * 288 + (blockIdx.x >> 3);
  const int bx  = wg & 3;
  const int by  = (wg >> 2) & 15;
  const int img = wg >> 6;
  const int gy0 = by * TROWS;
  const int gx0 = bx * TCOLS;
  const int lane = tid & 63;
  const int wv   = tid >> 6;

  {
    const unsigned short* s0 = wt + lane * 8;
    #pragma unroll
    for (int j = 0; j < 2; ++j) {
      const int i = wv * 2 + j;
      gload_lds16(s0 + i * 512, &Ws[0][i * 1024]);
    }
  }
  {
    const int xi = tid & 31;
    const int cq = tid >> 5;
    const int c0 = cq * 4;
    const int kg = c0 >> 3;
    const int bo = (c0 & 7) * 2;
    const float* pbase = xin + ((size_t)img * C_IN + c0) * HW + gx0 + xi;
    #pragma unroll
    for (int r = 0; r < HROWS; ++r) {
      const int gy = gy0 - 1 + r;
      float f0 = 0.f, f1 = 0.f, f2 = 0.f, f3 = 0.f;
      if (gy >= 0 && gy < Himg) {
        const float* p = pbase + (size_t)gy * Wimg;
        f0 = p[0]; f1 = p[HW]; f2 = p[2 * HW]; f3 = p[3 * HW];
      }
      const int pix = r * HCOLS + 1 + xi;
      *(uint2*)(&Xs[kg * XKSTR + pix * 16 + bo]) = make_uint2(pack2(f0, f1), pack2(f2, f3));
    }
  }
  #pragma unroll
  for (int it = 0; it < 3; ++it) {
    const int idx = tid + it * 512;
    if (idx < 2 * HROWS * C_IN) {
      const int side = (idx >= HROWS * C_IN) ? 1 : 0;
      const int rem  = idx - side * HROWS * C_IN;
      const int c = rem & 63;
      const int r = rem >> 6;
      const int gy = gy0 - 1 + r;
      const int gx = side ? (gx0 + TCOLS) : (gx0 - 1);
      float f = 0.f;
      if (gy >= 0 && gy < Himg && gx >= 0 && gx < Wimg)
        f = xin[((size_t)img * C_IN + c) * HW + (size_t)gy * Wimg + gx];
      const int pix = r * HCOLS + (side ? (HCOLS - 1) : 0);
      union { __bf16 h; unsigned short s; } u; u.h = (__bf16)f;
      *(unsigned short*)(&Xs[(c >> 3) * XKSTR + pix * 16 + (c & 7) * 2]) = u.s;
    }
  }

  const int lpx = lane & 31;
  const int lkh = lane >> 5;
  const int wm  = wv & 1;
  const int wn  = wv >> 1;

  f32x16 acc[2][2];
  #pragma unroll
  for (int mf = 0; mf < 2; ++mf)
    #pragma unroll
    for (int nf = 0; nf < 2; ++nf)
      acc[mf][nf] = (f32x16)(0.f);

  const int abase = lkh * 2048 + (wm * 64 + lpx) * 16;
  const int xbase = lkh * XKSTR;

  __syncthreads();

  for (int t = 0; t < 9; ++t) {
    if (t < 8) {
      const unsigned short* sn = wt + (t + 1) * 8192 + lane * 8;
      unsigned char* db = Ws[(t + 1) & 1];
      #pragma unroll
      for (int j = 0; j < 2; ++j) {
        const int i = wv * 2 + j;
        gload_lds16(sn + i * 512, &db[i * 1024]);
      }
    }
    const int dy = (t >= 6) ? 2 : (t >= 3 ? 1 : 0);
    const int dx = t - dy * 3;
    const unsigned char* wsb = Ws[t & 1];
    int boff[2];
    #pragma unroll
    for (int nf = 0; nf < 2; ++nf)
      boff[nf] = xbase + ((wn * 2 + nf + dy) * HCOLS + dx + lpx) * 16;
    #pragma unroll
    for (int sh = 0; sh < 2; ++sh) {
      bf16x8 A[2][2], B[2][2];
      #pragma unroll
      for (int ss = 0; ss < 2; ++ss) {
        const int ks = sh * 2 + ss;
        #pragma unroll
        for (int mf = 0; mf < 2; ++mf)
          A[mf][ss] = *(const bf16x8*)&wsb[abase + mf * 512 + ks * 4096];
        #pragma unroll
        for (int nf = 0; nf < 2; ++nf)
          B[nf][ss] = *(const bf16x8*)&Xs[boff[nf] + ks * 2 * XKSTR];
      }
      __builtin_amdgcn_s_setprio(1);
      #pragma unroll
      for (int ss = 0; ss < 2; ++ss)
        #pragma unroll
        for (int mf = 0; mf < 2; ++mf)
          #pragma unroll
          for (int nf = 0; nf < 2; ++nf)
            acc[mf][nf] = __builtin_amdgcn_mfma_f32_32x32x16_bf16(A[mf][ss], B[nf][ss], acc[mf][nf], 0, 0, 0);
      __builtin_amdgcn_s_setprio(0);
    }
    __syncthreads();
  }

  float4 bq[2][4];
  #pragma unroll
  for (int mf = 0; mf < 2; ++mf)
    #pragma unroll
    for (int rq = 0; rq < 4; ++rq)
      bq[mf][rq] = *(const float4*)(bias + wm * 64 + mf * 32 + rq * 8 + lkh * 4);

  #pragma unroll
  for (int nf = 0; nf < 2; ++nf) {
    const int y = gy0 + wn * 2 + nf;
    float* op = out + (size_t)img * C_OUT * HW + (size_t)y * Wimg + gx0 + lpx;
    #pragma unroll
    for (int mf = 0; mf < 2; ++mf) {
      #pragma unroll
      for (int r = 0; r < 16; ++r) {
        const int co = wm * 64 + mf * 32 + (r & 3) + 8 * (r >> 2) + lkh * 4;
        op[(size_t)co * HW] = acc[mf][nf][r] + ((const float*)&bq[mf][r >> 2])[r & 3];
      }
    }
  }
}

extern "C" void kernel_launch(void* const* d_in, const int* in_sizes, int n_in,
                              void* d_out, int out_size, void* d_ws, size_t ws_size,
                              hipStream_t stream) {
  const float* x    = (const float*)d_in[0];
  const float* w    = (const float*)d_in[1];
  const float* bias = (const float*)d_in[2];
  float* out = (float*)d_out;
  unsigned short* wt = (unsigned short*)d_ws;                       // 144 KB
  unsigned short* xb = (unsigned short*)((char*)d_ws + XB_OFF);     // 74.3 MB padded bf16 cells

  wt_transform<<<(9 * C_OUT * C_IN + 255) / 256, 256, 0, stream>>>(w, wt);

  if (ws_size >= WS_NEED) {
    const int ncell = 36 * 8 * 130 * 130;
    xcvt<<<(ncell + 255) / 256, 256, 0, stream>>>(x, xb);
    conv_pre<<<dim3(2304), 512, 0, stream>>>(xb, wt, bias, out);
  } else {
    conv_fb<<<dim3(2304), 512, 0, stream>>>(x, wt, bias, out);
  }
}